// Round 4
// baseline (1217.118 us; speedup 1.0000x reference)
//
#include <hip/hip_runtime.h>

typedef __bf16 bf16;
typedef bf16 bf16x4 __attribute__((ext_vector_type(4)));
typedef bf16 bf16x8 __attribute__((ext_vector_type(8)));
typedef float f32x4 __attribute__((ext_vector_type(4)));

static constexpr int BATCH = 16;
static constexpr int SEQ   = 2048;  // N
static constexpr int DH    = 512;   // H (== M)
static constexpr int ROWS  = BATCH * SEQ;  // 32768

__device__ __forceinline__ f32x4 mfma16(bf16x8 a, bf16x8 b, f32x4 c) {
    return __builtin_amdgcn_mfma_f32_16x16x32_bf16(a, b, c, 0, 0, 0);
}

// async global->LDS, 16B per lane. dst must be wave-uniform base (HW adds lane*16).
__device__ __forceinline__ void gl_lds16(const bf16* g, bf16* l) {
    __builtin_amdgcn_global_load_lds((const __attribute__((address_space(1))) void*)g,
                                     (__attribute__((address_space(3))) void*)l, 16, 0, 0);
}

// ---------------- fp32 -> bf16 (vectorized) ----------------
__global__ void cvt_bf16_kernel(const float* __restrict__ in, bf16* __restrict__ out, int n4) {
    int i = blockIdx.x * blockDim.x + threadIdx.x;
    const int stride = gridDim.x * blockDim.x;
    for (; i < n4; i += stride) {
        f32x4 f = *reinterpret_cast<const f32x4*>(in + (size_t)i * 4);
        bf16x4 o;
        o[0] = (bf16)f[0]; o[1] = (bf16)f[1]; o[2] = (bf16)f[2]; o[3] = (bf16)f[3];
        *reinterpret_cast<bf16x4*>(out + (size_t)i * 4) = o;
    }
}

// ---------------- weight [K=512][N=512] fp32 -> [N][K] bf16 ----------------
__global__ void cvt_wT_kernel(const float* __restrict__ in, bf16* __restrict__ out) {
    int idx = blockIdx.x * 256 + threadIdx.x;  // idx = n*512 + k
    int n = idx >> 9, k = idx & 511;
    out[idx] = (bf16)in[k * 512 + n];
}

// ---------------- GEMM: Y = relu(X[R,512] @ W[512,512] + b), LDS staged ----
// Wt is [n][k]. 128x128 tile, BK=64, double-buffered LDS via global_load_lds,
// XOR-swizzled (block^(row&7)) so ds_read_b128 is conflict-free.
// OMODE 0: bf16 out. 1: bf16 out + transposed copy [B][512][2048]. 2: fp32 out.
template <int OMODE>
__global__ __launch_bounds__(256, 2)
void gemm_relu_kernel(const bf16* __restrict__ X, const bf16* __restrict__ Wt,
                      const float* __restrict__ bias,
                      bf16* __restrict__ Y, bf16* __restrict__ Yt,
                      float* __restrict__ Yf)
{
    __shared__ bf16 Xl[2][128 * 64];
    __shared__ bf16 Wl[2][128 * 64];

    const int tid = threadIdx.x;
    const int lane = tid & 63, wid = tid >> 6;
    const int wr = wid >> 1, wc = wid & 1;
    const int r0 = blockIdx.x * 128;
    const int c0 = blockIdx.y * 128;
    const int lrow = lane & 15, lhi = lane >> 4;

    const int srow = tid >> 3;                // 0..31 within call
    const int skb  = (tid & 7) ^ (srow & 7);  // pre-swizzled source block
    const int sdst = wid * 512;               // this wave's 1KB chunk

    auto stage = [&](int buf, int kc) {
        const bf16* xs = X + (size_t)r0 * 512 + kc * 64;
        const bf16* ws = Wt + (size_t)c0 * 512 + kc * 64;
        #pragma unroll
        for (int c = 0; c < 4; ++c) {
            const int row = c * 32 + srow;
            gl_lds16(xs + (size_t)row * 512 + skb * 8, &Xl[buf][c * 2048 + sdst]);
        }
        #pragma unroll
        for (int c = 0; c < 4; ++c) {
            const int row = c * 32 + srow;
            gl_lds16(ws + (size_t)row * 512 + skb * 8, &Wl[buf][c * 2048 + sdst]);
        }
    };

    f32x4 acc[4][4] = {};

    stage(0, 0);
    __syncthreads();

    for (int t = 0; t < 8; ++t) {
        const int buf = t & 1;
        if (t + 1 < 8) stage(buf ^ 1, t + 1);
        #pragma unroll
        for (int kk = 0; kk < 2; ++kk) {
            bf16x8 af[4], bfr[4];
            const int kb = kk * 4 + lhi;
            #pragma unroll
            for (int tt = 0; tt < 4; ++tt) {
                const int ra = wr * 64 + tt * 16 + lrow;
                af[tt] = *reinterpret_cast<const bf16x8*>(&Xl[buf][ra * 64 + ((kb ^ (ra & 7)) * 8)]);
            }
            #pragma unroll
            for (int tt = 0; tt < 4; ++tt) {
                const int rb = wc * 64 + tt * 16 + lrow;
                bfr[tt] = *reinterpret_cast<const bf16x8*>(&Wl[buf][rb * 64 + ((kb ^ (rb & 7)) * 8)]);
            }
            #pragma unroll
            for (int i = 0; i < 4; ++i)
                #pragma unroll
                for (int j = 0; j < 4; ++j)
                    acc[i][j] = mfma16(af[i], bfr[j], acc[i][j]);
        }
        __syncthreads();
    }

    #pragma unroll
    for (int i = 0; i < 4; ++i) {
        #pragma unroll
        for (int j = 0; j < 4; ++j) {
            const int col = c0 + wc * 64 + j * 16 + lrow;
            const float bb = bias[col];
            #pragma unroll
            for (int rg = 0; rg < 4; ++rg) {
                const int r = r0 + wr * 64 + i * 16 + lhi * 4 + rg;
                float y = acc[i][j][rg] + bb;
                y = y > 0.f ? y : 0.f;
                if (OMODE == 2) {
                    Yf[(size_t)r * 512 + col] = y;
                } else {
                    Y[(size_t)r * 512 + col] = (bf16)y;
                    if (OMODE == 1) {
                        const int bi = r >> 11, nn = r & 2047;
                        Yt[((size_t)bi * 512 + col) * 2048 + nn] = (bf16)y;
                    }
                }
            }
        }
    }
}

// ---------------- fused attention ----------------
// scores = (Q K^T) * (-A); att = softmax(scores); O = att @ V + V  (bf16 out)
// Block: 32 q-rows, 4 waves, 256 threads. KVBLK=64.
// K tile in LDS (global_load_lds, XOR-swizzled). Vt + Q + A in registers.
// 2 barriers/iter + one final barrier before epilogue (l_lds hazard).
__global__ __launch_bounds__(256, 2)
void attn_kernel(const bf16* __restrict__ Q, const bf16* __restrict__ K,
                 const bf16* __restrict__ Vt, const bf16* __restrict__ V,
                 const float* __restrict__ A, bf16* __restrict__ O)
{
    __shared__ bf16 K_lds[64 * 512];    // [kv-row][depth] swizzled, 64KB
    __shared__ bf16 P_lds[32 * 64];     // swizzled, 4KB
    __shared__ float m_lds[32], l_lds[32], sc_lds[32];
    __shared__ float mxp_lds[2][32], sump_lds[2][32];

    const int tid = threadIdx.x;
    const int lane = tid & 63, wid = tid >> 6;
    const int wr = wid >> 1, wc = wid & 1;
    const int lrow = lane & 15, lhi = lane >> 4;

    // XCD-aware mapping: XCD x handles batches {2x, 2x+1} (K/V L2/L3 locality)
    const int id = blockIdx.x;
    const int y = id >> 3;
    const int bb = 2 * (id & 7) + (y >> 6);
    const int n0 = (y & 63) * 32;
    const int srow_base = wr * 16 + lhi * 4;

    if (tid < 32) { m_lds[tid] = -1e30f; l_lds[tid] = 0.f; }

    const bf16* Kbase  = K + (size_t)bb * SEQ * DH;
    const bf16* Vtbase = Vt + (size_t)bb * DH * SEQ;

    // stage K[0]: 16 rows per wave
    #pragma unroll
    for (int c = 0; c < 16; ++c) {
        const int row = wid * 16 + c;
        gl_lds16(Kbase + (size_t)row * DH + ((lane ^ (row & 7)) * 8), &K_lds[row * 512]);
    }

    // Q fragments resident (16 x 16B)
    bf16x8 qf[16];
    {
        const bf16* qp = Q + (size_t)(bb * SEQ + n0 + wr * 16 + lrow) * DH + lhi * 8;
        #pragma unroll
        for (int kk = 0; kk < 16; ++kk)
            qf[kk] = *reinterpret_cast<const bf16x8*>(qp + kk * 32);
    }

    __syncthreads();

    f32x4 acc[2][8] = {};  // O: [q-tile (2x16)][h-tile (8x16 of this wave's 128-slice)]

    for (int it = 0; it < 32; ++it) {
        const int m0 = it * 64;

        // A loads (HBM, consumed after QK^T)
        float av0[4], av1[4];
        {
            const float* ap = A + ((size_t)bb * SEQ + n0 + srow_base) * SEQ + m0 + wc * 32 + lrow;
            #pragma unroll
            for (int rg = 0; rg < 4; ++rg) {
                av0[rg] = ap[(size_t)rg * SEQ];
                av1[rg] = ap[(size_t)rg * SEQ + 16];
            }
        }
        // Vt prefetch to regs (L2/L3), consumed in PV
        bf16x8 vf[8][2];
        {
            const bf16* vp = Vtbase + (size_t)(wid * 128 + lrow) * SEQ + m0 + lhi * 8;
            #pragma unroll
            for (int ht = 0; ht < 8; ++ht)
                #pragma unroll
                for (int kc = 0; kc < 2; ++kc)
                    vf[ht][kc] = *reinterpret_cast<const bf16x8*>(vp + (size_t)(ht * 16) * SEQ + kc * 32);
        }

        // ---- phase 1: S = Q K^T from K_lds ----
        f32x4 s0 = {}, s1 = {};
        {
            const int kr0 = wc * 32 + lrow, kr1 = kr0 + 16;
            #pragma unroll
            for (int kk = 0; kk < 16; ++kk) {
                const int kb = kk * 4 + lhi;
                bf16x8 k0 = *reinterpret_cast<const bf16x8*>(&K_lds[kr0 * 512 + ((kb ^ (kr0 & 7)) * 8)]);
                bf16x8 k1 = *reinterpret_cast<const bf16x8*>(&K_lds[kr1 * 512 + ((kb ^ (kr1 & 7)) * 8)]);
                s0 = mfma16(qf[kk], k0, s0);
                s1 = mfma16(qf[kk], k1, s1);
            }
        }
        // scores * (-A), per-row max over this wave's 32 cols
        float x0[4], x1[4];
        #pragma unroll
        for (int rg = 0; rg < 4; ++rg) {
            x0[rg] = s0[rg] * (-av0[rg]);
            x1[rg] = s1[rg] * (-av1[rg]);
            float m = fmaxf(x0[rg], x1[rg]);
            m = fmaxf(m, __shfl_xor(m, 1));
            m = fmaxf(m, __shfl_xor(m, 2));
            m = fmaxf(m, __shfl_xor(m, 4));
            m = fmaxf(m, __shfl_xor(m, 8));
            if (lrow == 0) mxp_lds[wc][srow_base + rg] = m;
        }
        __syncthreads();  // B1

        // stage K[it+1] (drains at B2; consumed next iter)
        if (it + 1 < 32) {
            #pragma unroll
            for (int c = 0; c < 16; ++c) {
                const int row = wid * 16 + c;
                gl_lds16(Kbase + (size_t)(m0 + 64 + row) * DH + ((lane ^ (row & 7)) * 8),
                         &K_lds[row * 512]);
            }
        }

        // ---- phase 2: softmax in-register, P -> LDS ----
        #pragma unroll
        for (int rg = 0; rg < 4; ++rg) {
            const int row = srow_base + rg;
            const float mt = fmaxf(mxp_lds[0][row], mxp_lds[1][row]);
            const float mo = m_lds[row];
            const float mn = fmaxf(mo, mt);
            const float p0 = __expf(x0[rg] - mn);
            const float p1 = __expf(x1[rg] - mn);
            const int c0i = wc * 32 + lrow, c1i = c0i + 16;
            P_lds[row * 64 + (((c0i >> 3) ^ (row & 7)) * 8) + (c0i & 7)] = (bf16)p0;
            P_lds[row * 64 + (((c1i >> 3) ^ (row & 7)) * 8) + (c1i & 7)] = (bf16)p1;
            float s = p0 + p1;
            s += __shfl_xor(s, 1);
            s += __shfl_xor(s, 2);
            s += __shfl_xor(s, 4);
            s += __shfl_xor(s, 8);
            if (lrow == 0) {
                sump_lds[wc][row] = s;
                if (wc == 0) { sc_lds[row] = __expf(mo - mn); m_lds[row] = mn; }
            }
        }
        __syncthreads();  // B2

        // l update (ordered before epilogue reads by the post-loop barrier)
        if (tid < 32) l_lds[tid] = l_lds[tid] * sc_lds[tid] + sump_lds[0][tid] + sump_lds[1][tid];

        // ---- phase 3: rescale + PV (Vt from regs) ----
        #pragma unroll
        for (int rt = 0; rt < 2; ++rt) {
            #pragma unroll
            for (int rg = 0; rg < 4; ++rg) {
                const float sc = sc_lds[rt * 16 + lhi * 4 + rg];
                #pragma unroll
                for (int ht = 0; ht < 8; ++ht) acc[rt][ht][rg] *= sc;
            }
        }
        bf16x8 pf[2][2];
        #pragma unroll
        for (int rt = 0; rt < 2; ++rt) {
            const int prow = rt * 16 + lrow;
            #pragma unroll
            for (int kc = 0; kc < 2; ++kc)
                pf[rt][kc] = *reinterpret_cast<const bf16x8*>(
                    &P_lds[prow * 64 + (((kc * 4 + lhi) ^ (prow & 7)) * 8)]);
        }
        #pragma unroll
        for (int ht = 0; ht < 8; ++ht)
            #pragma unroll
            for (int kc = 0; kc < 2; ++kc)
                #pragma unroll
                for (int rt = 0; rt < 2; ++rt)
                    acc[rt][ht] = mfma16(pf[rt][kc], vf[ht][kc], acc[rt][ht]);
        // no end-of-iter barrier: next iter's B1/B2 order all intra-loop LDS hazards
    }

    __syncthreads();  // final: order last l_lds update before cross-wave epilogue reads

    // ---- epilogue: /l, + V, store bf16 ----
    #pragma unroll
    for (int rt = 0; rt < 2; ++rt) {
        #pragma unroll
        for (int rg = 0; rg < 4; ++rg) {
            const int row = rt * 16 + lhi * 4 + rg;
            const float inv = 1.f / l_lds[row];
            const size_t rbase = (size_t)(bb * SEQ + n0 + row) * DH;
            #pragma unroll
            for (int ht = 0; ht < 8; ++ht) {
                const int col = wid * 128 + ht * 16 + lrow;
                const float vv = (float)V[rbase + col];
                O[rbase + col] = (bf16)(acc[rt][ht][rg] * inv + vv);
            }
        }
    }
}

extern "C" void kernel_launch(void* const* d_in, const int* in_sizes, int n_in,
                              void* d_out, int out_size, void* d_ws, size_t ws_size,
                              hipStream_t stream) {
    const float* A    = (const float*)d_in[0];
    const float* h    = (const float*)d_in[1];
    const float* Wv1  = (const float*)d_in[2];
    const float* bv1  = (const float*)d_in[3];
    const float* Wv2  = (const float*)d_in[4];
    const float* bv2  = (const float*)d_in[5];
    const float* Wk   = (const float*)d_in[6];   // NOTE: Wk before Wq in dict order
    const float* bk   = (const float*)d_in[7];
    const float* Wq   = (const float*)d_in[8];
    const float* bq   = (const float*)d_in[9];
    const float* Wout = (const float*)d_in[10];
    const float* bout = (const float*)d_in[11];
    float* out = (float*)d_out;

    char* ws = (char*)d_ws;
    const size_t SZ = (size_t)ROWS * 512 * sizeof(bf16);  // 33.5 MB
    bf16* hb   = (bf16*)(ws + 0 * SZ);  // h in bf16; later reused as attention output
    bf16* tq   = (bf16*)(ws + 1 * SZ);  // t = relu(h@Wv1), later overwritten with q
    bf16* kb   = (bf16*)(ws + 2 * SZ);
    bf16* vb   = (bf16*)(ws + 3 * SZ);
    bf16* vtb  = (bf16*)(ws + 4 * SZ);  // v transposed: [B][H][N]
    bf16* wbase = (bf16*)(ws + 5 * SZ); // 5 x 512KB bf16 weights
    bf16* Wv1t  = wbase + 0 * 262144;
    bf16* Wv2t  = wbase + 1 * 262144;
    bf16* Wqt   = wbase + 2 * 262144;
    bf16* Wkt   = wbase + 3 * 262144;
    bf16* Woutt = wbase + 4 * 262144;
    bf16* ob = hb;  // attention output aliases hb (hb dead after k projection)

    cvt_bf16_kernel<<<4096, 256, 0, stream>>>(h, hb, ROWS * 512 / 4);
    cvt_wT_kernel<<<1024, 256, 0, stream>>>(Wv1, Wv1t);
    cvt_wT_kernel<<<1024, 256, 0, stream>>>(Wv2, Wv2t);
    cvt_wT_kernel<<<1024, 256, 0, stream>>>(Wq, Wqt);
    cvt_wT_kernel<<<1024, 256, 0, stream>>>(Wk, Wkt);
    cvt_wT_kernel<<<1024, 256, 0, stream>>>(Wout, Woutt);

    dim3 gg(ROWS / 128, 512 / 128);  // (256, 4)
    gemm_relu_kernel<0><<<gg, 256, 0, stream>>>(hb, Wv1t, bv1, tq, nullptr, nullptr);  // t
    gemm_relu_kernel<1><<<gg, 256, 0, stream>>>(tq, Wv2t, bv2, vb, vtb, nullptr);      // v + vT
    gemm_relu_kernel<0><<<gg, 256, 0, stream>>>(hb, Wqt, bq, tq, nullptr, nullptr);    // q (over t)
    gemm_relu_kernel<0><<<gg, 256, 0, stream>>>(hb, Wkt, bk, kb, nullptr, nullptr);    // k

    attn_kernel<<<dim3(1024), 256, 0, stream>>>(tq, kb, vtb, vb, A, ob);

    gemm_relu_kernel<2><<<gg, 256, 0, stream>>>(ob, Woutt, bout, nullptr, nullptr, out);
}

// Round 5
// 833.754 us; speedup vs baseline: 1.4598x; 1.4598x over previous
//
#include <hip/hip_runtime.h>

typedef __bf16 bf16;
typedef bf16 bf16x4 __attribute__((ext_vector_type(4)));
typedef bf16 bf16x8 __attribute__((ext_vector_type(8)));
typedef float f32x4 __attribute__((ext_vector_type(4)));

static constexpr int BATCH = 16;
static constexpr int SEQ   = 2048;  // N
static constexpr int DH    = 512;   // H (== M)
static constexpr int ROWS  = BATCH * SEQ;  // 32768

__device__ __forceinline__ f32x4 mfma16(bf16x8 a, bf16x8 b, f32x4 c) {
    return __builtin_amdgcn_mfma_f32_16x16x32_bf16(a, b, c, 0, 0, 0);
}

// async global->LDS, 16B per lane. dst must be wave-uniform base (HW adds lane*16).
__device__ __forceinline__ void gl_lds16(const bf16* g, bf16* l) {
    __builtin_amdgcn_global_load_lds((const __attribute__((address_space(1))) void*)g,
                                     (__attribute__((address_space(3))) void*)l, 16, 0, 0);
}

// ---------------- fp32 -> bf16 (vectorized) ----------------
__global__ void cvt_bf16_kernel(const float* __restrict__ in, bf16* __restrict__ out, int n4) {
    int i = blockIdx.x * blockDim.x + threadIdx.x;
    const int stride = gridDim.x * blockDim.x;
    for (; i < n4; i += stride) {
        f32x4 f = *reinterpret_cast<const f32x4*>(in + (size_t)i * 4);
        bf16x4 o;
        o[0] = (bf16)f[0]; o[1] = (bf16)f[1]; o[2] = (bf16)f[2]; o[3] = (bf16)f[3];
        *reinterpret_cast<bf16x4*>(out + (size_t)i * 4) = o;
    }
}

// ---------------- weight [K=512][N=512] fp32 -> [N][K] bf16 ----------------
__global__ void cvt_wT_kernel(const float* __restrict__ in, bf16* __restrict__ out) {
    int idx = blockIdx.x * 256 + threadIdx.x;  // idx = n*512 + k
    int n = idx >> 9, k = idx & 511;
    out[idx] = (bf16)in[k * 512 + n];
}

// ---------------- GEMM: Y = relu(X[R,512] @ W[512,512] + b), LDS staged ----
// Wt is [n][k]. 128x128 tile, BK=64, double-buffered LDS via global_load_lds,
// XOR-swizzled (block^(row&7)) so ds_read_b128 is conflict-free.
// OMODE 0: bf16 out. 1: bf16 out + transposed copy [B][512][2048]. 2: fp32 out.
template <int OMODE>
__global__ __launch_bounds__(256, 2)
void gemm_relu_kernel(const bf16* __restrict__ X, const bf16* __restrict__ Wt,
                      const float* __restrict__ bias,
                      bf16* __restrict__ Y, bf16* __restrict__ Yt,
                      float* __restrict__ Yf)
{
    __shared__ bf16 Xl[2][128 * 64];
    __shared__ bf16 Wl[2][128 * 64];

    const int tid = threadIdx.x;
    const int lane = tid & 63, wid = tid >> 6;
    const int wr = wid >> 1, wc = wid & 1;
    const int r0 = blockIdx.x * 128;
    const int c0 = blockIdx.y * 128;
    const int lrow = lane & 15, lhi = lane >> 4;

    const int srow = tid >> 3;                // 0..31 within call
    const int skb  = (tid & 7) ^ (srow & 7);  // pre-swizzled source block
    const int sdst = wid * 512;               // this wave's 1KB chunk

    auto stage = [&](int buf, int kc) {
        const bf16* xs = X + (size_t)r0 * 512 + kc * 64;
        const bf16* ws = Wt + (size_t)c0 * 512 + kc * 64;
        #pragma unroll
        for (int c = 0; c < 4; ++c) {
            const int row = c * 32 + srow;
            gl_lds16(xs + (size_t)row * 512 + skb * 8, &Xl[buf][c * 2048 + sdst]);
        }
        #pragma unroll
        for (int c = 0; c < 4; ++c) {
            const int row = c * 32 + srow;
            gl_lds16(ws + (size_t)row * 512 + skb * 8, &Wl[buf][c * 2048 + sdst]);
        }
    };

    f32x4 acc[4][4] = {};

    stage(0, 0);
    __syncthreads();

    for (int t = 0; t < 8; ++t) {
        const int buf = t & 1;
        if (t + 1 < 8) stage(buf ^ 1, t + 1);
        #pragma unroll
        for (int kk = 0; kk < 2; ++kk) {
            bf16x8 af[4], bfr[4];
            const int kb = kk * 4 + lhi;
            #pragma unroll
            for (int tt = 0; tt < 4; ++tt) {
                const int ra = wr * 64 + tt * 16 + lrow;
                af[tt] = *reinterpret_cast<const bf16x8*>(&Xl[buf][ra * 64 + ((kb ^ (ra & 7)) * 8)]);
            }
            #pragma unroll
            for (int tt = 0; tt < 4; ++tt) {
                const int rb = wc * 64 + tt * 16 + lrow;
                bfr[tt] = *reinterpret_cast<const bf16x8*>(&Wl[buf][rb * 64 + ((kb ^ (rb & 7)) * 8)]);
            }
            #pragma unroll
            for (int i = 0; i < 4; ++i)
                #pragma unroll
                for (int j = 0; j < 4; ++j)
                    acc[i][j] = mfma16(af[i], bfr[j], acc[i][j]);
        }
        __syncthreads();
    }

    #pragma unroll
    for (int i = 0; i < 4; ++i) {
        #pragma unroll
        for (int j = 0; j < 4; ++j) {
            const int col = c0 + wc * 64 + j * 16 + lrow;
            const float bb = bias[col];
            #pragma unroll
            for (int rg = 0; rg < 4; ++rg) {
                const int r = r0 + wr * 64 + i * 16 + lhi * 4 + rg;
                float y = acc[i][j][rg] + bb;
                y = y > 0.f ? y : 0.f;
                if (OMODE == 2) {
                    Yf[(size_t)r * 512 + col] = y;
                } else {
                    Y[(size_t)r * 512 + col] = (bf16)y;
                    if (OMODE == 1) {
                        const int bi = r >> 11, nn = r & 2047;
                        Yt[((size_t)bi * 512 + col) * 2048 + nn] = (bf16)y;
                    }
                }
            }
        }
    }
}

// ---------------- fused attention ----------------
// scores = (Q K^T) * (-A); att = softmax(scores); O = att @ V + V  (bf16 out)
// Block: 128 q-rows, 8 waves, 512 threads. KVBLK=32. Grid 256 = 1 block/CU.
// Wave w: owns q-rows [16w,16w+16) for QK^T + softmax (full 32-col strip ->
// wave-local softmax, m/l in registers), and h-slice [64w,64w+64) for PV.
// K double-buffered in LDS, staged one full iteration ahead (global_load_lds,
// XOR-swizzled). Vt + A register-prefetched at iter top. P + sc double-buffered.
// ONE barrier per iteration covers all LDS hazards.
__global__ __launch_bounds__(512, 2)
void attn_kernel(const bf16* __restrict__ Q, const bf16* __restrict__ K,
                 const bf16* __restrict__ Vt, const bf16* __restrict__ V,
                 const float* __restrict__ A, bf16* __restrict__ O)
{
    __shared__ bf16 K_lds[2][32 * 512];   // 2 x 32KB, swizzled
    __shared__ bf16 P_lds[2][128 * 40];   // stride 40 (80B rows): 2-way-free b128 reads
    __shared__ float sc_lds[2][128];
    __shared__ float l_lds[128];

    const int tid = threadIdx.x;
    const int lane = tid & 63, wid = tid >> 6;
    const int lrow = lane & 15, lhi = lane >> 4;

    // XCD x handles batches {2x, 2x+1}; 16 q-tiles per batch
    const int id = blockIdx.x;
    const int r = id >> 3;
    const int bb = 2 * (id & 7) + (r & 1);
    const int n0 = (r >> 1) * 128;

    const bf16* Kbase  = K + (size_t)bb * SEQ * DH;
    const bf16* Vtbase = Vt + (size_t)bb * DH * SEQ;

    // stage K[0] -> buf 0 (32 rows x 512, 4 rows/wave)
    #pragma unroll
    for (int c = 0; c < 4; ++c) {
        const int row = wid * 4 + c;
        gl_lds16(Kbase + (size_t)row * DH + ((lane ^ (row & 7)) * 8), &K_lds[0][row * 512]);
    }

    // Q resident: wave w rows 16w..16w+16, full depth (64 VGPR)
    bf16x8 qf[16];
    {
        const bf16* qp = Q + (size_t)(bb * SEQ + n0 + wid * 16 + lrow) * DH + lhi * 8;
        #pragma unroll
        for (int kk = 0; kk < 16; ++kk)
            qf[kk] = *reinterpret_cast<const bf16x8*>(qp + kk * 32);
    }

    float m_r[4], l_r[4];
    #pragma unroll
    for (int rg = 0; rg < 4; ++rg) { m_r[rg] = -1e30f; l_r[rg] = 0.f; }

    f32x4 acc[8][4] = {};  // [q-row-tile 0..7][h-tile 0..3 of this wave's 64-col slice]

    __syncthreads();

    for (int it = 0; it < 64; ++it) {
        const int m0 = it * 32;
        const int buf = it & 1;

        // stage K[it+1] into other buffer (drains at this iter's barrier; ~full-iter window)
        if (it + 1 < 64) {
            #pragma unroll
            for (int c = 0; c < 4; ++c) {
                const int row = wid * 4 + c;
                gl_lds16(Kbase + (size_t)(m0 + 32 + row) * DH + ((lane ^ (row & 7)) * 8),
                         &K_lds[buf ^ 1][row * 512]);
            }
        }
        // Vt register prefetch (consumed in PV after the barrier)
        bf16x8 vf[4];
        {
            const bf16* vp = Vtbase + (size_t)(wid * 64 + lrow) * SEQ + m0 + lhi * 8;
            #pragma unroll
            for (int h = 0; h < 4; ++h)
                vf[h] = *reinterpret_cast<const bf16x8*>(vp + (size_t)(h * 16) * SEQ);
        }
        // A register prefetch (consumed right after QK^T)
        float av0[4], av1[4];
        {
            const float* ap = A + ((size_t)bb * SEQ + n0 + wid * 16 + lhi * 4) * SEQ + m0 + lrow;
            #pragma unroll
            for (int rg = 0; rg < 4; ++rg) {
                av0[rg] = ap[(size_t)rg * SEQ];
                av1[rg] = ap[(size_t)rg * SEQ + 16];
            }
        }

        // ---- QK^T: S[16 rows x 32 cols] per wave, from K_lds[buf] ----
        f32x4 s0 = {}, s1 = {};
        #pragma unroll
        for (int kk = 0; kk < 16; ++kk) {
            const int ks = kk * 4 + lhi;
            bf16x8 k0 = *reinterpret_cast<const bf16x8*>(
                &K_lds[buf][lrow * 512 + ((ks ^ (lrow & 7)) * 8)]);
            bf16x8 k1 = *reinterpret_cast<const bf16x8*>(
                &K_lds[buf][(lrow + 16) * 512 + ((ks ^ ((lrow + 16) & 7)) * 8)]);
            s0 = mfma16(qf[kk], k0, s0);
            s1 = mfma16(qf[kk], k1, s1);
        }

        // ---- wave-local online softmax (rows fully inside this wave) ----
        #pragma unroll
        for (int rg = 0; rg < 4; ++rg) {
            const float x0 = s0[rg] * (-av0[rg]);
            const float x1 = s1[rg] * (-av1[rg]);
            float mx = fmaxf(x0, x1);
            mx = fmaxf(mx, __shfl_xor(mx, 1));
            mx = fmaxf(mx, __shfl_xor(mx, 2));
            mx = fmaxf(mx, __shfl_xor(mx, 4));
            mx = fmaxf(mx, __shfl_xor(mx, 8));
            const float mn = fmaxf(m_r[rg], mx);
            const float scv = __expf(m_r[rg] - mn);
            const float p0 = __expf(x0 - mn);
            const float p1 = __expf(x1 - mn);
            float s = p0 + p1;
            s += __shfl_xor(s, 1);
            s += __shfl_xor(s, 2);
            s += __shfl_xor(s, 4);
            s += __shfl_xor(s, 8);
            l_r[rg] = l_r[rg] * scv + s;
            m_r[rg] = mn;
            const int row_l = wid * 16 + lhi * 4 + rg;
            P_lds[buf][row_l * 40 + lrow]      = (bf16)p0;
            P_lds[buf][row_l * 40 + 16 + lrow] = (bf16)p1;
            if (lrow == 0) sc_lds[buf][row_l] = scv;
        }

        __syncthreads();  // single barrier: P/sc visible; K[it+1] stage drained

        // ---- PV: rescale + accumulate (P from LDS, Vt from regs) ----
        #pragma unroll
        for (int t = 0; t < 8; ++t) {
            const f32x4 sc4 = *reinterpret_cast<const f32x4*>(&sc_lds[buf][t * 16 + lhi * 4]);
            #pragma unroll
            for (int h = 0; h < 4; ++h)
                #pragma unroll
                for (int rg = 0; rg < 4; ++rg)
                    acc[t][h][rg] *= sc4[rg];
            const bf16x8 pf = *reinterpret_cast<const bf16x8*>(
                &P_lds[buf][(t * 16 + lrow) * 40 + lhi * 8]);
            #pragma unroll
            for (int h = 0; h < 4; ++h)
                acc[t][h] = mfma16(pf, vf[h], acc[t][h]);
        }
        // no second barrier: next iter writes P/sc[buf^1] and stages K[buf];
        // all conflicting accesses are separated by this iter's / next iter's barrier
    }

    // ---- epilogue: publish l, then /l, +V, store ----
    if (lrow == 0) {
        #pragma unroll
        for (int rg = 0; rg < 4; ++rg)
            l_lds[wid * 16 + lhi * 4 + rg] = l_r[rg];
    }
    __syncthreads();

    #pragma unroll
    for (int t = 0; t < 8; ++t) {
        #pragma unroll
        for (int rg = 0; rg < 4; ++rg) {
            const int row = t * 16 + lhi * 4 + rg;
            const float inv = 1.f / l_lds[row];
            const size_t rbase = (size_t)(bb * SEQ + n0 + row) * DH;
            #pragma unroll
            for (int h = 0; h < 4; ++h) {
                const int col = wid * 64 + h * 16 + lrow;
                const float vv = (float)V[rbase + col];
                O[rbase + col] = (bf16)(acc[t][h][rg] * inv + vv);
            }
        }
    }
}

extern "C" void kernel_launch(void* const* d_in, const int* in_sizes, int n_in,
                              void* d_out, int out_size, void* d_ws, size_t ws_size,
                              hipStream_t stream) {
    const float* A    = (const float*)d_in[0];
    const float* h    = (const float*)d_in[1];
    const float* Wv1  = (const float*)d_in[2];
    const float* bv1  = (const float*)d_in[3];
    const float* Wv2  = (const float*)d_in[4];
    const float* bv2  = (const float*)d_in[5];
    const float* Wk   = (const float*)d_in[6];   // NOTE: Wk before Wq in dict order
    const float* bk   = (const float*)d_in[7];
    const float* Wq   = (const float*)d_in[8];
    const float* bq   = (const float*)d_in[9];
    const float* Wout = (const float*)d_in[10];
    const float* bout = (const float*)d_in[11];
    float* out = (float*)d_out;

    char* ws = (char*)d_ws;
    const size_t SZ = (size_t)ROWS * 512 * sizeof(bf16);  // 33.5 MB
    bf16* hb   = (bf16*)(ws + 0 * SZ);  // h in bf16; later reused as attention output
    bf16* tq   = (bf16*)(ws + 1 * SZ);  // t = relu(h@Wv1), later overwritten with q
    bf16* kb   = (bf16*)(ws + 2 * SZ);
    bf16* vb   = (bf16*)(ws + 3 * SZ);
    bf16* vtb  = (bf16*)(ws + 4 * SZ);  // v transposed: [B][H][N]
    bf16* wbase = (bf16*)(ws + 5 * SZ); // 5 x 512KB bf16 weights
    bf16* Wv1t  = wbase + 0 * 262144;
    bf16* Wv2t  = wbase + 1 * 262144;
    bf16* Wqt   = wbase + 2 * 262144;
    bf16* Wkt   = wbase + 3 * 262144;
    bf16* Woutt = wbase + 4 * 262144;
    bf16* ob = hb;  // attention output aliases hb (hb dead after k projection)

    cvt_bf16_kernel<<<4096, 256, 0, stream>>>(h, hb, ROWS * 512 / 4);
    cvt_wT_kernel<<<1024, 256, 0, stream>>>(Wv1, Wv1t);
    cvt_wT_kernel<<<1024, 256, 0, stream>>>(Wv2, Wv2t);
    cvt_wT_kernel<<<1024, 256, 0, stream>>>(Wq, Wqt);
    cvt_wT_kernel<<<1024, 256, 0, stream>>>(Wk, Wkt);
    cvt_wT_kernel<<<1024, 256, 0, stream>>>(Wout, Woutt);

    dim3 gg(ROWS / 128, 512 / 128);  // (256, 4)
    gemm_relu_kernel<0><<<gg, 256, 0, stream>>>(hb, Wv1t, bv1, tq, nullptr, nullptr);  // t
    gemm_relu_kernel<1><<<gg, 256, 0, stream>>>(tq, Wv2t, bv2, vb, vtb, nullptr);      // v + vT
    gemm_relu_kernel<0><<<gg, 256, 0, stream>>>(hb, Wqt, bq, tq, nullptr, nullptr);    // q (over t)
    gemm_relu_kernel<0><<<gg, 256, 0, stream>>>(hb, Wkt, bk, kb, nullptr, nullptr);    // k

    attn_kernel<<<dim3(256), 512, 0, stream>>>(tq, kb, vtb, vb, A, ob);

    gemm_relu_kernel<2><<<gg, 256, 0, stream>>>(ob, Woutt, bout, nullptr, nullptr, out);
}

// Round 7
// 558.212 us; speedup vs baseline: 2.1804x; 1.4936x over previous
//
#include <hip/hip_runtime.h>

typedef __bf16 bf16;
typedef bf16 bf16x4 __attribute__((ext_vector_type(4)));
typedef bf16 bf16x8 __attribute__((ext_vector_type(8)));
typedef float f32x4 __attribute__((ext_vector_type(4)));

static constexpr int BATCH = 16;
static constexpr int SEQ   = 2048;  // N
static constexpr int DH    = 512;   // H (== M)
static constexpr int ROWS  = BATCH * SEQ;  // 32768

__device__ __forceinline__ f32x4 mfma16(bf16x8 a, bf16x8 b, f32x4 c) {
    return __builtin_amdgcn_mfma_f32_16x16x32_bf16(a, b, c, 0, 0, 0);
}

// async global->LDS, 16B per lane. dst must be wave-uniform base (HW adds lane*16).
__device__ __forceinline__ void gl_lds16(const bf16* g, bf16* l) {
    __builtin_amdgcn_global_load_lds((const __attribute__((address_space(1))) void*)g,
                                     (__attribute__((address_space(3))) void*)l, 16, 0, 0);
}

// ---------------- fp32 -> bf16 (vectorized) ----------------
__global__ void cvt_bf16_kernel(const float* __restrict__ in, bf16* __restrict__ out, int n4) {
    int i = blockIdx.x * blockDim.x + threadIdx.x;
    const int stride = gridDim.x * blockDim.x;
    for (; i < n4; i += stride) {
        f32x4 f = *reinterpret_cast<const f32x4*>(in + (size_t)i * 4);
        bf16x4 o;
        o[0] = (bf16)f[0]; o[1] = (bf16)f[1]; o[2] = (bf16)f[2]; o[3] = (bf16)f[3];
        *reinterpret_cast<bf16x4*>(out + (size_t)i * 4) = o;
    }
}

// ---------------- weight [K=512][N=512] fp32 -> [N][K] bf16 ----------------
__global__ void cvt_wT_kernel(const float* __restrict__ in, bf16* __restrict__ out) {
    int idx = blockIdx.x * 256 + threadIdx.x;  // idx = n*512 + k
    int n = idx >> 9, k = idx & 511;
    out[idx] = (bf16)in[k * 512 + n];
}

// ---------------- GEMM: Y = relu(X[R,512] @ W[512,512] + b), LDS staged ----
template <int OMODE>
__global__ __launch_bounds__(256, 2)
void gemm_relu_kernel(const bf16* __restrict__ X, const bf16* __restrict__ Wt,
                      const float* __restrict__ bias,
                      bf16* __restrict__ Y, bf16* __restrict__ Yt,
                      float* __restrict__ Yf)
{
    __shared__ bf16 Xl[2][128 * 64];
    __shared__ bf16 Wl[2][128 * 64];

    const int tid = threadIdx.x;
    const int lane = tid & 63, wid = tid >> 6;
    const int wr = wid >> 1, wc = wid & 1;
    const int r0 = blockIdx.x * 128;
    const int c0 = blockIdx.y * 128;
    const int lrow = lane & 15, lhi = lane >> 4;

    const int srow = tid >> 3;                // 0..31 within call
    const int skb  = (tid & 7) ^ (srow & 7);  // pre-swizzled source block
    const int sdst = wid * 512;               // this wave's 1KB chunk

    auto stage = [&](int buf, int kc) {
        const bf16* xs = X + (size_t)r0 * 512 + kc * 64;
        const bf16* ws = Wt + (size_t)c0 * 512 + kc * 64;
        #pragma unroll
        for (int c = 0; c < 4; ++c) {
            const int row = c * 32 + srow;
            gl_lds16(xs + (size_t)row * 512 + skb * 8, &Xl[buf][c * 2048 + sdst]);
        }
        #pragma unroll
        for (int c = 0; c < 4; ++c) {
            const int row = c * 32 + srow;
            gl_lds16(ws + (size_t)row * 512 + skb * 8, &Wl[buf][c * 2048 + sdst]);
        }
    };

    f32x4 acc[4][4] = {};

    stage(0, 0);
    __syncthreads();

    for (int t = 0; t < 8; ++t) {
        const int buf = t & 1;
        if (t + 1 < 8) stage(buf ^ 1, t + 1);
        #pragma unroll
        for (int kk = 0; kk < 2; ++kk) {
            bf16x8 af[4], bfr[4];
            const int kb = kk * 4 + lhi;
            #pragma unroll
            for (int tt = 0; tt < 4; ++tt) {
                const int ra = wr * 64 + tt * 16 + lrow;
                af[tt] = *reinterpret_cast<const bf16x8*>(&Xl[buf][ra * 64 + ((kb ^ (ra & 7)) * 8)]);
            }
            #pragma unroll
            for (int tt = 0; tt < 4; ++tt) {
                const int rb = wc * 64 + tt * 16 + lrow;
                bfr[tt] = *reinterpret_cast<const bf16x8*>(&Wl[buf][rb * 64 + ((kb ^ (rb & 7)) * 8)]);
            }
            #pragma unroll
            for (int i = 0; i < 4; ++i)
                #pragma unroll
                for (int j = 0; j < 4; ++j)
                    acc[i][j] = mfma16(af[i], bfr[j], acc[i][j]);
        }
        __syncthreads();
    }

    #pragma unroll
    for (int i = 0; i < 4; ++i) {
        #pragma unroll
        for (int j = 0; j < 4; ++j) {
            const int col = c0 + wc * 64 + j * 16 + lrow;
            const float bb = bias[col];
            #pragma unroll
            for (int rg = 0; rg < 4; ++rg) {
                const int r = r0 + wr * 64 + i * 16 + lhi * 4 + rg;
                float y = acc[i][j][rg] + bb;
                y = y > 0.f ? y : 0.f;
                if (OMODE == 2) {
                    Yf[(size_t)r * 512 + col] = y;
                } else {
                    Y[(size_t)r * 512 + col] = (bf16)y;
                    if (OMODE == 1) {
                        const int bi = r >> 11, nn = r & 2047;
                        Yt[((size_t)bi * 512 + col) * 2048 + nn] = (bf16)y;
                    }
                }
            }
        }
    }
}

// ---------------- fused attention ----------------
// scores = (Q K^T) * (-A); att = softmax(scores); O = att @ V + V  (bf16 out)
// Block: 64 q-rows, 8 waves, 512 threads. KVBLK=64 (32 iters).
// Wave (wr,wc): QK^T computes S[16 rows x 32-col strip wc] -> each wave reads
// only its 32-row K strip from LDS. K double-buffered (2x64KB), staged one
// full iteration ahead. Register softmax with mxp/sump cross-strip combine.
// Vt + A in registers (A double-buffered one iter ahead). B1 = raw lgkm
// barrier (vmem stays in flight); B2 = __syncthreads (drains stage one
// phase before consumption). P_lds row stride 72 (64 cols + 8 pad).
__global__ __launch_bounds__(512, 2)
void attn_kernel(const bf16* __restrict__ Q, const bf16* __restrict__ K,
                 const bf16* __restrict__ Vt, const bf16* __restrict__ V,
                 const float* __restrict__ A, bf16* __restrict__ O)
{
    __shared__ bf16 K_lds[2][64 * 512];   // 2 x 64KB, XOR-swizzled rows
    __shared__ bf16 P_lds[64 * 72];       // stride 72 (144B rows): 2-way-max b128 reads
    __shared__ float sc_lds[64], l_lds[64];
    __shared__ float mxp_lds[2][64], sump_lds[2][64];

    const int tid = threadIdx.x;
    const int lane = tid & 63, wid = tid >> 6;
    const int wr = wid >> 1, wc = wid & 1;
    const int lrow = lane & 15, lhi = lane >> 4;

    // XCD x handles batches {2x, 2x+1}; K+Vt of one batch ~4MB ≈ L2-resident.
    const int id = blockIdx.x;
    const int xcd = id & 7, j = id >> 3;
    const int bb = 2 * xcd + (j >> 5);
    const int n0 = (j & 31) * 64;
    const int srow_base = wr * 16 + lhi * 4;

    const bf16* Kbase  = K + (size_t)bb * SEQ * DH;
    const bf16* Vtbase = Vt + (size_t)bb * DH * SEQ;

    // stage K[0] -> buf 0 (64 rows, 8 per wave)
    #pragma unroll
    for (int c = 0; c < 8; ++c) {
        const int row = wid * 8 + c;
        gl_lds16(Kbase + (size_t)row * DH + ((lane ^ (row & 7)) * 8), &K_lds[0][row * 512]);
    }

    // Q resident: rows n0 + wr*16 + lrow (wc pair loads same rows)
    bf16x8 qf[16];
    {
        const bf16* qp = Q + (size_t)(bb * SEQ + n0 + wr * 16 + lrow) * DH + lhi * 8;
        #pragma unroll
        for (int kk = 0; kk < 16; ++kk)
            qf[kk] = *reinterpret_cast<const bf16x8*>(qp + kk * 32);
    }

    // A for it=0 (double-buffered in regs thereafter)
    float av_c[8];
    {
        const float* ap = A + ((size_t)bb * SEQ + n0 + srow_base) * SEQ + wc * 32 + lrow;
        #pragma unroll
        for (int rg = 0; rg < 4; ++rg) {
            av_c[rg]     = ap[(size_t)rg * SEQ];
            av_c[rg + 4] = ap[(size_t)rg * SEQ + 16];
        }
    }

    float m_r[4], l_r[4];
    #pragma unroll
    for (int rg = 0; rg < 4; ++rg) { m_r[rg] = -1e30f; l_r[rg] = 0.f; }

    f32x4 acc[4][4] = {};  // [q-row-tile][h-tile of this wave's 64-col slice]

    __syncthreads();

    for (int it = 0; it < 32; ++it) {
        const int m0 = it * 64;
        const int buf = it & 1;

        // stage K[it+1] into other buffer (drains at B2; consumed next iter)
        if (it + 1 < 32) {
            #pragma unroll
            for (int c = 0; c < 8; ++c) {
                const int row = wid * 8 + c;
                gl_lds16(Kbase + (size_t)(m0 + 64 + row) * DH + ((lane ^ (row & 7)) * 8),
                         &K_lds[buf ^ 1][row * 512]);
            }
        }
        // Vt regs for this iter (consumed in PV after B2)
        bf16x8 vf[4][2];
        {
            const bf16* vp = Vtbase + (size_t)(wid * 64 + lrow) * SEQ + m0 + lhi * 8;
            #pragma unroll
            for (int ht = 0; ht < 4; ++ht)
                #pragma unroll
                for (int kc = 0; kc < 2; ++kc)
                    vf[ht][kc] = *reinterpret_cast<const bf16x8*>(
                        vp + (size_t)(ht * 16) * SEQ + kc * 32);
        }
        // A for it+1 (consumed next iter; ~full-iter latency window)
        float av_n[8];
        if (it + 1 < 32) {
            const float* ap = A + ((size_t)bb * SEQ + n0 + srow_base) * SEQ + m0 + 64 + wc * 32 + lrow;
            #pragma unroll
            for (int rg = 0; rg < 4; ++rg) {
                av_n[rg]     = ap[(size_t)rg * SEQ];
                av_n[rg + 4] = ap[(size_t)rg * SEQ + 16];
            }
        }

        // ---- QK^T: S[16 x 32-col strip] from K_lds[buf] (32 rows per wave) ----
        f32x4 s0 = {}, s1 = {};
        {
            const int kr0 = wc * 32 + lrow, kr1 = kr0 + 16;
            #pragma unroll
            for (int kk = 0; kk < 16; ++kk) {
                const int ks = kk * 4 + lhi;
                bf16x8 k0 = *reinterpret_cast<const bf16x8*>(
                    &K_lds[buf][kr0 * 512 + ((ks ^ (kr0 & 7)) * 8)]);
                bf16x8 k1 = *reinterpret_cast<const bf16x8*>(
                    &K_lds[buf][kr1 * 512 + ((ks ^ (kr1 & 7)) * 8)]);
                s0 = mfma16(qf[kk], k0, s0);
                s1 = mfma16(qf[kk], k1, s1);
            }
        }

        // scores * (-A); per-row strip max; publish to mxp
        float x0[4], x1[4];
        #pragma unroll
        for (int rg = 0; rg < 4; ++rg) {
            x0[rg] = s0[rg] * (-av_c[rg]);
            x1[rg] = s1[rg] * (-av_c[rg + 4]);
            float mx = fmaxf(x0[rg], x1[rg]);
            mx = fmaxf(mx, __shfl_xor(mx, 1));
            mx = fmaxf(mx, __shfl_xor(mx, 2));
            mx = fmaxf(mx, __shfl_xor(mx, 4));
            mx = fmaxf(mx, __shfl_xor(mx, 8));
            if (lrow == 0) mxp_lds[wc][srow_base + rg] = mx;
        }

        // B1: raw barrier, LDS ops only — vmem (K stage, Vt, A) stays in flight
        asm volatile("s_waitcnt lgkmcnt(0)" ::: "memory");
        __builtin_amdgcn_s_barrier();
        __builtin_amdgcn_sched_barrier(0);

        // ---- softmax (m duplicated across wc pair; l tracked by wc==0) ----
        float sc_keep[4], s_keep[4];
        #pragma unroll
        for (int rg = 0; rg < 4; ++rg) {
            const int row = srow_base + rg;
            const float mt = fmaxf(mxp_lds[0][row], mxp_lds[1][row]);
            const float mn = fmaxf(m_r[rg], mt);
            const float scv = __expf(m_r[rg] - mn);
            const float p0 = __expf(x0[rg] - mn);
            const float p1 = __expf(x1[rg] - mn);
            const int c0i = wc * 32 + lrow;
            P_lds[row * 72 + c0i]      = (bf16)p0;
            P_lds[row * 72 + c0i + 16] = (bf16)p1;
            float s = p0 + p1;
            s += __shfl_xor(s, 1);
            s += __shfl_xor(s, 2);
            s += __shfl_xor(s, 4);
            s += __shfl_xor(s, 8);
            m_r[rg] = mn;
            sc_keep[rg] = scv;
            s_keep[rg] = s;
            if (lrow == 0) {
                sump_lds[wc][row] = s;
                if (wc == 0) sc_lds[row] = scv;
            }
        }

        __syncthreads();  // B2: P/sc/sump visible; K[it+1] stage drained

        // l update (wc==0 waves, lane-duplicated)
        if (wc == 0) {
            #pragma unroll
            for (int rg = 0; rg < 4; ++rg)
                l_r[rg] = l_r[rg] * sc_keep[rg] + s_keep[rg] + sump_lds[1][srow_base + rg];
        }

        // ---- PV: rescale + accumulate (P from LDS, Vt from regs) ----
        #pragma unroll
        for (int t = 0; t < 4; ++t) {
            const f32x4 sc4 = *reinterpret_cast<const f32x4*>(&sc_lds[t * 16 + lhi * 4]);
            #pragma unroll
            for (int ht = 0; ht < 4; ++ht)
                #pragma unroll
                for (int rg = 0; rg < 4; ++rg)
                    acc[t][ht][rg] *= sc4[rg];
            bf16x8 pf[2];
            #pragma unroll
            for (int kc = 0; kc < 2; ++kc)
                pf[kc] = *reinterpret_cast<const bf16x8*>(
                    &P_lds[(t * 16 + lrow) * 72 + kc * 32 + lhi * 8]);
            #pragma unroll
            for (int ht = 0; ht < 4; ++ht)
                #pragma unroll
                for (int kc = 0; kc < 2; ++kc)
                    acc[t][ht] = mfma16(pf[kc], vf[ht][kc], acc[t][ht]);
        }

        // swap A buffers
        #pragma unroll
        for (int q = 0; q < 8; ++q) av_c[q] = av_n[q];
        // no trailing barrier: next iter's B1 (lgkm drain + s_barrier) orders the
        // P/sc/sump WAR; next iter's QK^T reads buf^1 data drained at this B2.
    }

    // publish l, then epilogue: /l, +V, store
    if (wc == 0 && lrow == 0) {
        #pragma unroll
        for (int rg = 0; rg < 4; ++rg)
            l_lds[srow_base + rg] = l_r[rg];
    }
    __syncthreads();

    #pragma unroll
    for (int t = 0; t < 4; ++t) {
        #pragma unroll
        for (int rg = 0; rg < 4; ++rg) {
            const int row = t * 16 + lhi * 4 + rg;
            const float inv = 1.f / l_lds[row];
            const size_t rbase = (size_t)(bb * SEQ + n0 + row) * DH;
            #pragma unroll
            for (int ht = 0; ht < 4; ++ht) {
                const int col = wid * 64 + ht * 16 + lrow;
                const float vv = (float)V[rbase + col];
                O[rbase + col] = (bf16)(acc[t][ht][rg] * inv + vv);
            }
        }
    }
}

extern "C" void kernel_launch(void* const* d_in, const int* in_sizes, int n_in,
                              void* d_out, int out_size, void* d_ws, size_t ws_size,
                              hipStream_t stream) {
    const float* A    = (const float*)d_in[0];
    const float* h    = (const float*)d_in[1];
    const float* Wv1  = (const float*)d_in[2];
    const float* bv1  = (const float*)d_in[3];
    const float* Wv2  = (const float*)d_in[4];
    const float* bv2  = (const float*)d_in[5];
    const float* Wk   = (const float*)d_in[6];   // NOTE: Wk before Wq in dict order
    const float* bk   = (const float*)d_in[7];
    const float* Wq   = (const float*)d_in[8];
    const float* bq   = (const float*)d_in[9];
    const float* Wout = (const float*)d_in[10];
    const float* bout = (const float*)d_in[11];
    float* out = (float*)d_out;

    char* ws = (char*)d_ws;
    const size_t SZ = (size_t)ROWS * 512 * sizeof(bf16);  // 33.5 MB
    bf16* hb   = (bf16*)(ws + 0 * SZ);  // h in bf16; later reused as attention output
    bf16* tq   = (bf16*)(ws + 1 * SZ);  // t = relu(h@Wv1), later overwritten with q
    bf16* kb   = (bf16*)(ws + 2 * SZ);
    bf16* vb   = (bf16*)(ws + 3 * SZ);
    bf16* vtb  = (bf16*)(ws + 4 * SZ);  // v transposed: [B][H][N]
    bf16* wbase = (bf16*)(ws + 5 * SZ); // 5 x 512KB bf16 weights
    bf16* Wv1t  = wbase + 0 * 262144;
    bf16* Wv2t  = wbase + 1 * 262144;
    bf16* Wqt   = wbase + 2 * 262144;
    bf16* Wkt   = wbase + 3 * 262144;
    bf16* Woutt = wbase + 4 * 262144;
    bf16* ob = hb;  // attention output aliases hb (hb dead after k projection)

    cvt_bf16_kernel<<<4096, 256, 0, stream>>>(h, hb, ROWS * 512 / 4);
    cvt_wT_kernel<<<1024, 256, 0, stream>>>(Wv1, Wv1t);
    cvt_wT_kernel<<<1024, 256, 0, stream>>>(Wv2, Wv2t);
    cvt_wT_kernel<<<1024, 256, 0, stream>>>(Wq, Wqt);
    cvt_wT_kernel<<<1024, 256, 0, stream>>>(Wk, Wkt);
    cvt_wT_kernel<<<1024, 256, 0, stream>>>(Wout, Woutt);

    dim3 gg(ROWS / 128, 512 / 128);  // (256, 4)
    gemm_relu_kernel<0><<<gg, 256, 0, stream>>>(hb, Wv1t, bv1, tq, nullptr, nullptr);  // t
    gemm_relu_kernel<1><<<gg, 256, 0, stream>>>(tq, Wv2t, bv2, vb, vtb, nullptr);      // v + vT
    gemm_relu_kernel<0><<<gg, 256, 0, stream>>>(hb, Wqt, bq, tq, nullptr, nullptr);    // q (over t)
    gemm_relu_kernel<0><<<gg, 256, 0, stream>>>(hb, Wkt, bk, kb, nullptr, nullptr);    // k

    attn_kernel<<<dim3(512), 512, 0, stream>>>(tq, kb, vtb, vb, A, ob);

    gemm_relu_kernel<2><<<gg, 256, 0, stream>>>(ob, Woutt, bout, nullptr, nullptr, out);
}

// Round 8
// 557.652 us; speedup vs baseline: 2.1826x; 1.0010x over previous
//
#include <hip/hip_runtime.h>

typedef __bf16 bf16;
typedef bf16 bf16x4 __attribute__((ext_vector_type(4)));
typedef bf16 bf16x8 __attribute__((ext_vector_type(8)));
typedef float f32x4 __attribute__((ext_vector_type(4)));

static constexpr int BATCH = 16;
static constexpr int SEQ   = 2048;  // N
static constexpr int DH    = 512;   // H (== M)
static constexpr int ROWS  = BATCH * SEQ;  // 32768

__device__ __forceinline__ f32x4 mfma16(bf16x8 a, bf16x8 b, f32x4 c) {
    return __builtin_amdgcn_mfma_f32_16x16x32_bf16(a, b, c, 0, 0, 0);
}

// async global->LDS, 16B per lane. dst must be wave-uniform base (HW adds lane*16).
__device__ __forceinline__ void gl_lds16(const bf16* g, bf16* l) {
    __builtin_amdgcn_global_load_lds((const __attribute__((address_space(1))) void*)g,
                                     (__attribute__((address_space(3))) void*)l, 16, 0, 0);
}

// ---------------- fp32 -> bf16 (vectorized) ----------------
__global__ void cvt_bf16_kernel(const float* __restrict__ in, bf16* __restrict__ out, int n4) {
    int i = blockIdx.x * blockDim.x + threadIdx.x;
    const int stride = gridDim.x * blockDim.x;
    for (; i < n4; i += stride) {
        f32x4 f = *reinterpret_cast<const f32x4*>(in + (size_t)i * 4);
        bf16x4 o;
        o[0] = (bf16)f[0]; o[1] = (bf16)f[1]; o[2] = (bf16)f[2]; o[3] = (bf16)f[3];
        *reinterpret_cast<bf16x4*>(out + (size_t)i * 4) = o;
    }
}

// ---------------- weight [K=512][N=512] fp32 -> [N][K] bf16 ----------------
__global__ void cvt_wT_kernel(const float* __restrict__ in, bf16* __restrict__ out) {
    int idx = blockIdx.x * 256 + threadIdx.x;  // idx = n*512 + k
    int n = idx >> 9, k = idx & 511;
    out[idx] = (bf16)in[k * 512 + n];
}

// ---------------- GEMM: Y = relu(X[R,512] @ W[512,512] + b), LDS staged ----
template <int OMODE>
__global__ __launch_bounds__(256, 2)
void gemm_relu_kernel(const bf16* __restrict__ X, const bf16* __restrict__ Wt,
                      const float* __restrict__ bias,
                      bf16* __restrict__ Y, bf16* __restrict__ Yt,
                      float* __restrict__ Yf)
{
    __shared__ bf16 Xl[2][128 * 64];
    __shared__ bf16 Wl[2][128 * 64];

    const int tid = threadIdx.x;
    const int lane = tid & 63, wid = tid >> 6;
    const int wr = wid >> 1, wc = wid & 1;
    const int r0 = blockIdx.x * 128;
    const int c0 = blockIdx.y * 128;
    const int lrow = lane & 15, lhi = lane >> 4;

    const int srow = tid >> 3;                // 0..31 within call
    const int skb  = (tid & 7) ^ (srow & 7);  // pre-swizzled source block
    const int sdst = wid * 512;               // this wave's 1KB chunk

    auto stage = [&](int buf, int kc) {
        const bf16* xs = X + (size_t)r0 * 512 + kc * 64;
        const bf16* ws = Wt + (size_t)c0 * 512 + kc * 64;
        #pragma unroll
        for (int c = 0; c < 4; ++c) {
            const int row = c * 32 + srow;
            gl_lds16(xs + (size_t)row * 512 + skb * 8, &Xl[buf][c * 2048 + sdst]);
        }
        #pragma unroll
        for (int c = 0; c < 4; ++c) {
            const int row = c * 32 + srow;
            gl_lds16(ws + (size_t)row * 512 + skb * 8, &Wl[buf][c * 2048 + sdst]);
        }
    };

    f32x4 acc[4][4] = {};

    stage(0, 0);
    __syncthreads();

    for (int t = 0; t < 8; ++t) {
        const int buf = t & 1;
        if (t + 1 < 8) stage(buf ^ 1, t + 1);
        #pragma unroll
        for (int kk = 0; kk < 2; ++kk) {
            bf16x8 af[4], bfr[4];
            const int kb = kk * 4 + lhi;
            #pragma unroll
            for (int tt = 0; tt < 4; ++tt) {
                const int ra = wr * 64 + tt * 16 + lrow;
                af[tt] = *reinterpret_cast<const bf16x8*>(&Xl[buf][ra * 64 + ((kb ^ (ra & 7)) * 8)]);
            }
            #pragma unroll
            for (int tt = 0; tt < 4; ++tt) {
                const int rb = wc * 64 + tt * 16 + lrow;
                bfr[tt] = *reinterpret_cast<const bf16x8*>(&Wl[buf][rb * 64 + ((kb ^ (rb & 7)) * 8)]);
            }
            #pragma unroll
            for (int i = 0; i < 4; ++i)
                #pragma unroll
                for (int j = 0; j < 4; ++j)
                    acc[i][j] = mfma16(af[i], bfr[j], acc[i][j]);
        }
        __syncthreads();
    }

    #pragma unroll
    for (int i = 0; i < 4; ++i) {
        #pragma unroll
        for (int j = 0; j < 4; ++j) {
            const int col = c0 + wc * 64 + j * 16 + lrow;
            const float bb = bias[col];
            #pragma unroll
            for (int rg = 0; rg < 4; ++rg) {
                const int r = r0 + wr * 64 + i * 16 + lhi * 4 + rg;
                float y = acc[i][j][rg] + bb;
                y = y > 0.f ? y : 0.f;
                if (OMODE == 2) {
                    Yf[(size_t)r * 512 + col] = y;
                } else {
                    Y[(size_t)r * 512 + col] = (bf16)y;
                    if (OMODE == 1) {
                        const int bi = r >> 11, nn = r & 2047;
                        Yt[((size_t)bi * 512 + col) * 2048 + nn] = (bf16)y;
                    }
                }
            }
        }
    }
}

// ---------------- fused attention ----------------
// scores = (Q K^T) * (-A); att = softmax(scores); O = att @ V + V  (bf16 out)
// Block: 64 q-rows, 8 waves, 512 threads. KVBLK=64 (32 iters).
// Wave (wr,wc): QK^T computes S[16 rows x 32-col strip wc] -> each wave reads
// only its 32-row K strip from LDS. K double-buffered (2x64KB), staged one
// full iteration ahead. Register softmax with mxp/sump cross-strip combine.
// Vt + A in registers (A double-buffered one iter ahead). B1 = raw lgkm
// barrier (vmem stays in flight); B2 = __syncthreads (drains stage one
// phase before consumption). P_lds row stride 72 (64 cols + 8 pad).
// __launch_bounds__(512, 1): LDS already caps us at 1 block/CU (2 waves/SIMD),
// so let the allocator use up to 256 VGPR — keeps Vt/A prefetches hoisted
// instead of sunk to their consumption points (R7 showed VGPR capped at 128
// = qf+acc alone, proving prefetches were being serialized at use sites).
__global__ __launch_bounds__(512, 1)
void attn_kernel(const bf16* __restrict__ Q, const bf16* __restrict__ K,
                 const bf16* __restrict__ Vt, const bf16* __restrict__ V,
                 const float* __restrict__ A, bf16* __restrict__ O)
{
    __shared__ bf16 K_lds[2][64 * 512];   // 2 x 64KB, XOR-swizzled rows
    __shared__ bf16 P_lds[64 * 72];       // stride 72 (144B rows): 2-way-max b128 reads
    __shared__ float sc_lds[64], l_lds[64];
    __shared__ float mxp_lds[2][64], sump_lds[2][64];

    const int tid = threadIdx.x;
    const int lane = tid & 63, wid = tid >> 6;
    const int wr = wid >> 1, wc = wid & 1;
    const int lrow = lane & 15, lhi = lane >> 4;

    // XCD x handles batches {2x, 2x+1}; K+Vt of one batch ~4MB ≈ L2-resident.
    const int id = blockIdx.x;
    const int xcd = id & 7, j = id >> 3;
    const int bb = 2 * xcd + (j >> 5);
    const int n0 = (j & 31) * 64;
    const int srow_base = wr * 16 + lhi * 4;

    const bf16* Kbase  = K + (size_t)bb * SEQ * DH;
    const bf16* Vtbase = Vt + (size_t)bb * DH * SEQ;

    // stage K[0] -> buf 0 (64 rows, 8 per wave)
    #pragma unroll
    for (int c = 0; c < 8; ++c) {
        const int row = wid * 8 + c;
        gl_lds16(Kbase + (size_t)row * DH + ((lane ^ (row & 7)) * 8), &K_lds[0][row * 512]);
    }

    // Q resident: rows n0 + wr*16 + lrow (wc pair loads same rows)
    bf16x8 qf[16];
    {
        const bf16* qp = Q + (size_t)(bb * SEQ + n0 + wr * 16 + lrow) * DH + lhi * 8;
        #pragma unroll
        for (int kk = 0; kk < 16; ++kk)
            qf[kk] = *reinterpret_cast<const bf16x8*>(qp + kk * 32);
    }

    // A for it=0 (double-buffered in regs thereafter)
    float av_c[8];
    {
        const float* ap = A + ((size_t)bb * SEQ + n0 + srow_base) * SEQ + wc * 32 + lrow;
        #pragma unroll
        for (int rg = 0; rg < 4; ++rg) {
            av_c[rg]     = ap[(size_t)rg * SEQ];
            av_c[rg + 4] = ap[(size_t)rg * SEQ + 16];
        }
    }

    float m_r[4], l_r[4];
    #pragma unroll
    for (int rg = 0; rg < 4; ++rg) { m_r[rg] = -1e30f; l_r[rg] = 0.f; }

    f32x4 acc[4][4] = {};  // [q-row-tile][h-tile of this wave's 64-col slice]

    __syncthreads();

    for (int it = 0; it < 32; ++it) {
        const int m0 = it * 64;
        const int buf = it & 1;

        // stage K[it+1] into other buffer (drains at B2; consumed next iter)
        if (it + 1 < 32) {
            #pragma unroll
            for (int c = 0; c < 8; ++c) {
                const int row = wid * 8 + c;
                gl_lds16(Kbase + (size_t)(m0 + 64 + row) * DH + ((lane ^ (row & 7)) * 8),
                         &K_lds[buf ^ 1][row * 512]);
            }
        }
        // Vt regs for this iter (consumed in PV after B2)
        bf16x8 vf[4][2];
        {
            const bf16* vp = Vtbase + (size_t)(wid * 64 + lrow) * SEQ + m0 + lhi * 8;
            #pragma unroll
            for (int ht = 0; ht < 4; ++ht)
                #pragma unroll
                for (int kc = 0; kc < 2; ++kc)
                    vf[ht][kc] = *reinterpret_cast<const bf16x8*>(
                        vp + (size_t)(ht * 16) * SEQ + kc * 32);
        }
        // A for it+1 (consumed next iter; ~full-iter latency window)
        float av_n[8];
        if (it + 1 < 32) {
            const float* ap = A + ((size_t)bb * SEQ + n0 + srow_base) * SEQ + m0 + 64 + wc * 32 + lrow;
            #pragma unroll
            for (int rg = 0; rg < 4; ++rg) {
                av_n[rg]     = ap[(size_t)rg * SEQ];
                av_n[rg + 4] = ap[(size_t)rg * SEQ + 16];
            }
        }

        // ---- QK^T: S[16 x 32-col strip] from K_lds[buf] (32 rows per wave) ----
        f32x4 s0 = {}, s1 = {};
        {
            const int kr0 = wc * 32 + lrow, kr1 = kr0 + 16;
            #pragma unroll
            for (int kk = 0; kk < 16; ++kk) {
                const int ks = kk * 4 + lhi;
                bf16x8 k0 = *reinterpret_cast<const bf16x8*>(
                    &K_lds[buf][kr0 * 512 + ((ks ^ (kr0 & 7)) * 8)]);
                bf16x8 k1 = *reinterpret_cast<const bf16x8*>(
                    &K_lds[buf][kr1 * 512 + ((ks ^ (kr1 & 7)) * 8)]);
                s0 = mfma16(qf[kk], k0, s0);
                s1 = mfma16(qf[kk], k1, s1);
            }
        }

        // scores * (-A); per-row strip max; publish to mxp
        float x0[4], x1[4];
        #pragma unroll
        for (int rg = 0; rg < 4; ++rg) {
            x0[rg] = s0[rg] * (-av_c[rg]);
            x1[rg] = s1[rg] * (-av_c[rg + 4]);
            float mx = fmaxf(x0[rg], x1[rg]);
            mx = fmaxf(mx, __shfl_xor(mx, 1));
            mx = fmaxf(mx, __shfl_xor(mx, 2));
            mx = fmaxf(mx, __shfl_xor(mx, 4));
            mx = fmaxf(mx, __shfl_xor(mx, 8));
            if (lrow == 0) mxp_lds[wc][srow_base + rg] = mx;
        }

        // B1: raw barrier, LDS ops only — vmem (K stage, Vt, A) stays in flight
        asm volatile("s_waitcnt lgkmcnt(0)" ::: "memory");
        __builtin_amdgcn_s_barrier();
        __builtin_amdgcn_sched_barrier(0);

        // ---- softmax (m duplicated across wc pair; l tracked by wc==0) ----
        float sc_keep[4], s_keep[4];
        #pragma unroll
        for (int rg = 0; rg < 4; ++rg) {
            const int row = srow_base + rg;
            const float mt = fmaxf(mxp_lds[0][row], mxp_lds[1][row]);
            const float mn = fmaxf(m_r[rg], mt);
            const float scv = __expf(m_r[rg] - mn);
            const float p0 = __expf(x0[rg] - mn);
            const float p1 = __expf(x1[rg] - mn);
            const int c0i = wc * 32 + lrow;
            P_lds[row * 72 + c0i]      = (bf16)p0;
            P_lds[row * 72 + c0i + 16] = (bf16)p1;
            float s = p0 + p1;
            s += __shfl_xor(s, 1);
            s += __shfl_xor(s, 2);
            s += __shfl_xor(s, 4);
            s += __shfl_xor(s, 8);
            m_r[rg] = mn;
            sc_keep[rg] = scv;
            s_keep[rg] = s;
            if (lrow == 0) {
                sump_lds[wc][row] = s;
                if (wc == 0) sc_lds[row] = scv;
            }
        }

        __syncthreads();  // B2: P/sc/sump visible; K[it+1] stage drained

        // l update (wc==0 waves, lane-duplicated)
        if (wc == 0) {
            #pragma unroll
            for (int rg = 0; rg < 4; ++rg)
                l_r[rg] = l_r[rg] * sc_keep[rg] + s_keep[rg] + sump_lds[1][srow_base + rg];
        }

        // ---- PV: rescale + accumulate (P from LDS, Vt from regs) ----
        #pragma unroll
        for (int t = 0; t < 4; ++t) {
            const f32x4 sc4 = *reinterpret_cast<const f32x4*>(&sc_lds[t * 16 + lhi * 4]);
            #pragma unroll
            for (int ht = 0; ht < 4; ++ht)
                #pragma unroll
                for (int rg = 0; rg < 4; ++rg)
                    acc[t][ht][rg] *= sc4[rg];
            bf16x8 pf[2];
            #pragma unroll
            for (int kc = 0; kc < 2; ++kc)
                pf[kc] = *reinterpret_cast<const bf16x8*>(
                    &P_lds[(t * 16 + lrow) * 72 + kc * 32 + lhi * 8]);
            #pragma unroll
            for (int ht = 0; ht < 4; ++ht)
                #pragma unroll
                for (int kc = 0; kc < 2; ++kc)
                    acc[t][ht] = mfma16(pf[kc], vf[ht][kc], acc[t][ht]);
        }

        // swap A buffers
        #pragma unroll
        for (int q = 0; q < 8; ++q) av_c[q] = av_n[q];
        // no trailing barrier: next iter's B1 (lgkm drain + s_barrier) orders the
        // P/sc/sump WAR; next iter's QK^T reads buf^1 data drained at this B2.
    }

    // publish l, then epilogue: /l, +V, store
    if (wc == 0 && lrow == 0) {
        #pragma unroll
        for (int rg = 0; rg < 4; ++rg)
            l_lds[srow_base + rg] = l_r[rg];
    }
    __syncthreads();

    #pragma unroll
    for (int t = 0; t < 4; ++t) {
        #pragma unroll
        for (int rg = 0; rg < 4; ++rg) {
            const int row = t * 16 + lhi * 4 + rg;
            const float inv = 1.f / l_lds[row];
            const size_t rbase = (size_t)(bb * SEQ + n0 + row) * DH;
            #pragma unroll
            for (int ht = 0; ht < 4; ++ht) {
                const int col = wid * 64 + ht * 16 + lrow;
                const float vv = (float)V[rbase + col];
                O[rbase + col] = (bf16)(acc[t][ht][rg] * inv + vv);
            }
        }
    }
}

extern "C" void kernel_launch(void* const* d_in, const int* in_sizes, int n_in,
                              void* d_out, int out_size, void* d_ws, size_t ws_size,
                              hipStream_t stream) {
    const float* A    = (const float*)d_in[0];
    const float* h    = (const float*)d_in[1];
    const float* Wv1  = (const float*)d_in[2];
    const float* bv1  = (const float*)d_in[3];
    const float* Wv2  = (const float*)d_in[4];
    const float* bv2  = (const float*)d_in[5];
    const float* Wk   = (const float*)d_in[6];   // NOTE: Wk before Wq in dict order
    const float* bk   = (const float*)d_in[7];
    const float* Wq   = (const float*)d_in[8];
    const float* bq   = (const float*)d_in[9];
    const float* Wout = (const float*)d_in[10];
    const float* bout = (const float*)d_in[11];
    float* out = (float*)d_out;

    char* ws = (char*)d_ws;
    const size_t SZ = (size_t)ROWS * 512 * sizeof(bf16);  // 33.5 MB
    bf16* hb   = (bf16*)(ws + 0 * SZ);  // h in bf16; later reused as attention output
    bf16* tq   = (bf16*)(ws + 1 * SZ);  // t = relu(h@Wv1), later overwritten with q
    bf16* kb   = (bf16*)(ws + 2 * SZ);
    bf16* vb   = (bf16*)(ws + 3 * SZ);
    bf16* vtb  = (bf16*)(ws + 4 * SZ);  // v transposed: [B][H][N]
    bf16* wbase = (bf16*)(ws + 5 * SZ); // 5 x 512KB bf16 weights
    bf16* Wv1t  = wbase + 0 * 262144;
    bf16* Wv2t  = wbase + 1 * 262144;
    bf16* Wqt   = wbase + 2 * 262144;
    bf16* Wkt   = wbase + 3 * 262144;
    bf16* Woutt = wbase + 4 * 262144;
    bf16* ob = hb;  // attention output aliases hb (hb dead after k projection)

    cvt_bf16_kernel<<<4096, 256, 0, stream>>>(h, hb, ROWS * 512 / 4);
    cvt_wT_kernel<<<1024, 256, 0, stream>>>(Wv1, Wv1t);
    cvt_wT_kernel<<<1024, 256, 0, stream>>>(Wv2, Wv2t);
    cvt_wT_kernel<<<1024, 256, 0, stream>>>(Wq, Wqt);
    cvt_wT_kernel<<<1024, 256, 0, stream>>>(Wk, Wkt);
    cvt_wT_kernel<<<1024, 256, 0, stream>>>(Wout, Woutt);

    dim3 gg(ROWS / 128, 512 / 128);  // (256, 4)
    gemm_relu_kernel<0><<<gg, 256, 0, stream>>>(hb, Wv1t, bv1, tq, nullptr, nullptr);  // t
    gemm_relu_kernel<1><<<gg, 256, 0, stream>>>(tq, Wv2t, bv2, vb, vtb, nullptr);      // v + vT
    gemm_relu_kernel<0><<<gg, 256, 0, stream>>>(hb, Wqt, bq, tq, nullptr, nullptr);    // q (over t)
    gemm_relu_kernel<0><<<gg, 256, 0, stream>>>(hb, Wkt, bk, kb, nullptr, nullptr);    // k

    attn_kernel<<<dim3(512), 512, 0, stream>>>(tq, kb, vtb, vb, A, ob);

    gemm_relu_kernel<2><<<gg, 256, 0, stream>>>(ob, Woutt, bout, nullptr, nullptr, out);
}